// Round 6
// baseline (221.289 us; speedup 1.0000x reference)
//
#include <hip/hip_runtime.h>
#include <math.h>

#define B_   4
#define S_   4096
#define D_   1024
#define HD_  64

// ---------------- split-K flash constants ----------------
#define CK            8          // k-tiles (of 64 keys) per chunk
#define CHUNKS_PER_B  288        // sum_{qi=0}^{63} (qi/8 + 1)
#define PSTRIDE       68         // floats per row in a partial slot (o[64], m, l, pad)
#define SLOT_F        (64 * PSTRIDE)

typedef float  f32x4  __attribute__((ext_vector_type(4)));
typedef __bf16 bf16x8 __attribute__((ext_vector_type(8)));

static __device__ __forceinline__ unsigned short f2bf(float f) {
    unsigned int u = __float_as_uint(f);
    u += 0x7FFFu + ((u >> 16) & 1u);          // round-to-nearest-even
    return (unsigned short)(u >> 16);
}

// ------------------------------------------------------------------
// Kernel 0: convert wq/wk/wv (fp32 [64][1024]) into wbf (bf16 [192][1024]).
// ------------------------------------------------------------------
__global__ __launch_bounds__(256) void convert_w(
    const float* __restrict__ wq, const float* __restrict__ wk,
    const float* __restrict__ wv, unsigned short* __restrict__ wbf)
{
    const int col = blockIdx.x;            // 0..191
    const int p = col >> 6, h = col & 63;
    const float* src = (p == 0 ? wq : (p == 1 ? wk : wv)) + (size_t)h * D_;
    const int t = threadIdx.x;
    const float4 v = ((const float4*)src)[t];
    ushort4 o;
    o.x = f2bf(v.x); o.y = f2bf(v.y); o.z = f2bf(v.z); o.w = f2bf(v.w);
    *(ushort4*)&wbf[(size_t)col * D_ + 4 * t] = o;
}

// ------------------------------------------------------------------
// Kernel 1: QKV projection via bf16 MFMA (16x16x32), register-prefetch
// double-buffered K-loop (one barrier per iteration).
// grid = (512, 2): 32 rows x 96 cols per block. LDS 36.9 KB -> 4/CU.
// Outputs bf16: qbf (pre-scaled 0.125), kbf row-major; vt[b][h][s].
// Fragment layouts (validated R3-R5):
//   A: lane elem j = A[m = lane&15][k = (lane>>4)*8 + j]
//   B: lane elem j = B[k = (lane>>4)*8 + j][n = lane&15]
//   C/D: reg r -> row = (lane>>4)*4 + r, col = lane&15
// ------------------------------------------------------------------
__global__ __launch_bounds__(256) void proj_mfma(
    const float* __restrict__ x, const unsigned short* __restrict__ wbf,
    const float* __restrict__ bq, const float* __restrict__ bk,
    const float* __restrict__ bv,
    unsigned short* __restrict__ qbf, unsigned short* __restrict__ kbf,
    unsigned short* __restrict__ vtb)
{
    __shared__ unsigned short xs[2][32][72];     // 2 x 4608 B
    __shared__ unsigned short wsh[2][96][72];    // 2 x 13824 B

    const int t = threadIdx.x;
    const int w = t >> 6, lane = t & 63;
    const int n = lane & 15, g = lane >> 4;
    const int koff = 8 * g;
    const int rt = w & 1, cg = w >> 1;
    const size_t row0 = (size_t)blockIdx.x * 32;
    const int colbase = 96 * blockIdx.y;

    // staging decode (constant per thread)
    const int xr0 = t >> 4, xc4 = (t & 15) * 4;            // x: 2 rows apart by 16
    const int wc0 = t >> 3, wg8 = (t & 7) * 8;             // w: 3 cols apart by 32

    float4 xr[2];
    uint4  wr[3];

    auto loadXW = [&](int chunk) {
        const int d0 = chunk * 64;
#pragma unroll
        for (int i = 0; i < 2; ++i)
            xr[i] = *(const float4*)&x[(row0 + xr0 + 16 * i) * D_ + d0 + xc4];
#pragma unroll
        for (int i = 0; i < 3; ++i)
            wr[i] = *(const uint4*)&wbf[(size_t)(colbase + wc0 + 32 * i) * D_ + d0 + wg8];
    };
    auto storeXW = [&](int buf) {
#pragma unroll
        for (int i = 0; i < 2; ++i) {
            ushort4 o;
            o.x = f2bf(xr[i].x); o.y = f2bf(xr[i].y);
            o.z = f2bf(xr[i].z); o.w = f2bf(xr[i].w);
            *(ushort4*)&xs[buf][xr0 + 16 * i][xc4] = o;
        }
#pragma unroll
        for (int i = 0; i < 3; ++i)
            *(uint4*)&wsh[buf][wc0 + 32 * i][wg8] = wr[i];
    };

    f32x4 acc[3];
#pragma unroll
    for (int i = 0; i < 3; ++i) acc[i] = (f32x4)0.f;

    // prologue: chunk0 -> buf0; prefetch chunk1 into regs
    loadXW(0);
    storeXW(0);
    loadXW(1);
    __syncthreads();

    for (int c = 0; c < 16; ++c) {
        const int cur = c & 1;
#pragma unroll
        for (int ks = 0; ks < 2; ++ks) {
            const int k0 = 32 * ks;
            const bf16x8 a = *(const bf16x8*)&xs[cur][16 * rt + n][k0 + koff];
#pragma unroll
            for (int ci = 0; ci < 3; ++ci) {
                const bf16x8 b = *(const bf16x8*)&wsh[cur][48 * cg + 16 * ci + n][k0 + koff];
                acc[ci] = __builtin_amdgcn_mfma_f32_16x16x32_bf16(a, b, acc[ci], 0, 0, 0);
            }
        }
        if (c < 15) {
            storeXW(1 - cur);            // chunk c+1 -> other buf (safe: last read at c-1)
            if (c < 14) loadXW(c + 2);   // prefetch next-next; lands during next compute
        }
        __syncthreads();
    }

    // epilogue
#pragma unroll
    for (int ci = 0; ci < 3; ++ci) {
        const int gct = 6 * blockIdx.y + 3 * cg + ci;
        const int p = gct >> 2, h0 = (gct & 3) * 16;
        const int h = h0 + n;
        const float bb = (p == 0 ? bq : (p == 1 ? bk : bv))[h];
        if (p == 2) {
            // v transposed: vt[b][h][s], 4 consecutive s packed
            const size_t grow0 = row0 + 16 * rt + 4 * g;
            const int bidx = (int)(grow0 >> 12);
            const int s0 = (int)(grow0 & 4095);
            ushort4 u;
            u.x = f2bf(acc[ci][0] + bb); u.y = f2bf(acc[ci][1] + bb);
            u.z = f2bf(acc[ci][2] + bb); u.w = f2bf(acc[ci][3] + bb);
            *(ushort4*)&vtb[((size_t)bidx * HD_ + h) * S_ + s0] = u;
        } else {
            unsigned short* outp = (p == 0 ? qbf : kbf);
            const float scale = (p == 0) ? 0.125f : 1.0f;
#pragma unroll
            for (int r = 0; r < 4; ++r) {
                const size_t grow = row0 + 16 * rt + 4 * g + r;
                outp[grow * HD_ + h] = f2bf((acc[ci][r] + bb) * scale);
            }
        }
    }
}

// ------------------------------------------------------------------
// Kernel 2: split-K causal flash attention, bf16 MFMA, bf16 inputs,
// register-prefetch K/V staging (loads for kt+1 in flight during
// compute of kt). Wave w owns q-rows 16w..16w+15.
// ------------------------------------------------------------------
__global__ __launch_bounds__(256) void flash_splitk(
    const unsigned short* __restrict__ qg, const unsigned short* __restrict__ kg,
    const unsigned short* __restrict__ vt, float* __restrict__ out,
    float* __restrict__ part)
{
    __shared__ unsigned short qsh[64][72];      // 9216 B  Q rows (pre-scaled)
    __shared__ unsigned short ksh[64][72];      // 9216 B  K rows
    __shared__ unsigned short vsh[64][72];      // 9216 B  vT[h][key]
    __shared__ unsigned short psh[4][16][72];   // 9216 B  per-wave P[q][key]

    const int t    = threadIdx.x;
    const int w    = t >> 6;
    const int lane = t & 63;
    const int n    = lane & 15;      // MFMA col index
    const int g    = lane >> 4;      // MFMA row group
    const int koff = 8 * g;
    const int b    = blockIdx.y;

    // decode blockIdx.x -> (qi, c)
    int qi = 0, rem = blockIdx.x;
    while (rem >= ((qi >> 3) + 1)) { rem -= (qi >> 3) + 1; ++qi; }
    const int c   = rem;
    const int kt0 = c * CK;
    const int kt1 = min(qi, kt0 + CK - 1);
    const int nc  = (qi >> 3) + 1;

    const size_t qtile = ((size_t)b * S_ + (size_t)qi * 64) * HD_;

    // staging decode
    const int sr = t >> 3, sg8 = (t & 7) * 8;   // 2 rows apart by 32

    // stage Q (once): 2 uint4/thread
    {
        const uint4* src = (const uint4*)(qg + qtile);
#pragma unroll
        for (int i = 0; i < 2; ++i) {
            int e = t + i * 256;                // 0..511
            int r = e >> 3, gg = e & 7;
            *(uint4*)&qsh[r][8 * gg] = src[e];
        }
    }

    uint4 kr[2], vr[2];
    auto loadKV = [&](int kt) {
        const size_t kvbase = ((size_t)b * S_ + (size_t)kt * 64) * HD_;
#pragma unroll
        for (int i = 0; i < 2; ++i)
            kr[i] = *(const uint4*)&kg[kvbase + (size_t)(sr + 32 * i) * HD_ + sg8];
#pragma unroll
        for (int i = 0; i < 2; ++i)
            vr[i] = *(const uint4*)&vt[((size_t)b * HD_ + (sr + 32 * i)) * S_ + kt * 64 + sg8];
    };
    auto storeKV = [&]() {
#pragma unroll
        for (int i = 0; i < 2; ++i) *(uint4*)&ksh[sr + 32 * i][sg8] = kr[i];
#pragma unroll
        for (int i = 0; i < 2; ++i) *(uint4*)&vsh[sr + 32 * i][sg8] = vr[i];
    };

    f32x4 o4[4];
#pragma unroll
    for (int i = 0; i < 4; ++i) o4[i] = (f32x4)0.f;
    float m_r = -INFINITY, l_r = 0.f;

    loadKV(kt0);                                 // prefetch first tile

    for (int kt = kt0; kt <= kt1; ++kt) {
        __syncthreads();                         // prev compute's LDS reads done
        storeKV();                               // waits vmcnt for this tile's loads
        if (kt < kt1) loadKV(kt + 1);            // in flight during compute below
        __syncthreads();

        // ---- S^T = K . Q^T : 4 m-tiles (keys) x 16 q ----
        f32x4 sc[4];
#pragma unroll
        for (int mt = 0; mt < 4; ++mt) sc[mt] = (f32x4)0.f;
#pragma unroll
        for (int ks = 0; ks < 2; ++ks) {
            const bf16x8 bq8 = *(const bf16x8*)&qsh[16 * w + n][32 * ks + koff];
#pragma unroll
            for (int mt = 0; mt < 4; ++mt) {
                const bf16x8 ak = *(const bf16x8*)&ksh[16 * mt + n][32 * ks + koff];
                sc[mt] = __builtin_amdgcn_mfma_f32_16x16x32_bf16(ak, bq8, sc[mt], 0, 0, 0);
            }
        }

        // ---- causal mask (diagonal k-tile only) ----
        if (kt == qi) {
            const int qloc = 16 * w + n;
#pragma unroll
            for (int mt = 0; mt < 4; ++mt)
#pragma unroll
                for (int r = 0; r < 4; ++r) {
                    const int kloc = 16 * mt + 4 * g + r;
                    if (kloc > qloc) sc[mt][r] = -INFINITY;
                }
        }

        // ---- online softmax per column q ----
        float mx = -INFINITY;
#pragma unroll
        for (int mt = 0; mt < 4; ++mt)
#pragma unroll
            for (int r = 0; r < 4; ++r) mx = fmaxf(mx, sc[mt][r]);
        mx = fmaxf(mx, __shfl_xor(mx, 16));
        mx = fmaxf(mx, __shfl_xor(mx, 32));

        const float m_new = fmaxf(m_r, mx);
        const float alpha = __expf(m_r - m_new);
        float psum = 0.f;
#pragma unroll
        for (int mt = 0; mt < 4; ++mt)
#pragma unroll
            for (int r = 0; r < 4; ++r) {
                const float p = __expf(sc[mt][r] - m_new);
                sc[mt][r] = p;
                psum += p;
            }
        psum += __shfl_xor(psum, 16);
        psum += __shfl_xor(psum, 32);
        l_r = l_r * alpha + psum;
        m_r = m_new;

        // rescale O rows (row q = 4g+r needs alpha of column 4g+r)
#pragma unroll
        for (int r = 0; r < 4; ++r) {
            const float ar = __shfl(alpha, 4 * g + r);
#pragma unroll
            for (int ht = 0; ht < 4; ++ht) o4[ht][r] *= ar;
        }

        // ---- pack P^T -> per-wave LDS p[q][key] ----
#pragma unroll
        for (int mt = 0; mt < 4; ++mt) {
            ushort4 u;
            u.x = f2bf(sc[mt][0]); u.y = f2bf(sc[mt][1]);
            u.z = f2bf(sc[mt][2]); u.w = f2bf(sc[mt][3]);
            *(ushort4*)&psh[w][n][16 * mt + 4 * g] = u;
        }
        // same-wave RAW on LDS: compiler inserts lgkmcnt wait; no barrier needed

        // ---- O += P . V ----
#pragma unroll
        for (int ks = 0; ks < 2; ++ks) {
            const bf16x8 ap = *(const bf16x8*)&psh[w][n][32 * ks + koff];
#pragma unroll
            for (int ht = 0; ht < 4; ++ht) {
                const bf16x8 bv8 = *(const bf16x8*)&vsh[16 * ht + n][32 * ks + koff];
                o4[ht] = __builtin_amdgcn_mfma_f32_16x16x32_bf16(ap, bv8, o4[ht], 0, 0, 0);
            }
        }
    }

    const size_t qbase = ((size_t)b * S_ + (size_t)qi * 64) * HD_;
    if (nc == 1) {
#pragma unroll
        for (int r = 0; r < 4; ++r) {
            const float lr = __shfl(l_r, 4 * g + r);
            const float inv = 1.f / lr;
            const size_t ob = qbase + (size_t)(16 * w + 4 * g + r) * HD_;
#pragma unroll
            for (int ht = 0; ht < 4; ++ht)
                out[ob + 16 * ht + n] = o4[ht][r] * inv;
        }
    } else {
        const size_t sb = ((size_t)b * CHUNKS_PER_B + blockIdx.x) * SLOT_F;
#pragma unroll
        for (int r = 0; r < 4; ++r) {
            const size_t pb = sb + (size_t)(16 * w + 4 * g + r) * PSTRIDE;
#pragma unroll
            for (int ht = 0; ht < 4; ++ht)
                part[pb + 16 * ht + n] = o4[ht][r];
        }
        if (g == 0) {
            part[sb + (size_t)(16 * w + n) * PSTRIDE + 64] = m_r;
            part[sb + (size_t)(16 * w + n) * PSTRIDE + 65] = l_r;
        }
    }
}

// ------------------------------------------------------------------
// Kernel 3: merge partials for qi >= CK.  grid = (56, B).
// ------------------------------------------------------------------
__global__ __launch_bounds__(256) void combine(
    const float* __restrict__ part, float* __restrict__ out)
{
    const int t  = threadIdx.x;
    const int qr = t >> 2, tc = t & 3;
    const int qi = blockIdx.x + CK;          // 8..63
    const int b  = blockIdx.y;
    const int nc = (qi >> 3) + 1;

    int cum = 0;
    for (int j = 0; j < qi; ++j) cum += (j >> 3) + 1;
    const size_t base0 = ((size_t)b * CHUNKS_PER_B + cum) * SLOT_F;

    float M = -INFINITY;
    for (int c0 = 0; c0 < nc; ++c0)
        M = fmaxf(M, part[base0 + (size_t)c0 * SLOT_F + qr * PSTRIDE + 64]);

    float L = 0.f;
    float o[16];
#pragma unroll
    for (int j = 0; j < 16; ++j) o[j] = 0.f;

    for (int c0 = 0; c0 < nc; ++c0) {
        const size_t sb = base0 + (size_t)c0 * SLOT_F + qr * PSTRIDE;
        const float m_c = part[sb + 64];
        const float l_c = part[sb + 65];
        const float w = __expf(m_c - M);
        L += w * l_c;
#pragma unroll
        for (int j = 0; j < 4; ++j) {
            const float4 ov = *(const float4*)&part[sb + tc * 16 + 4 * j];
            o[4 * j + 0] += w * ov.x; o[4 * j + 1] += w * ov.y;
            o[4 * j + 2] += w * ov.z; o[4 * j + 3] += w * ov.w;
        }
    }

    const float inv = 1.f / L;
    const size_t qbase = ((size_t)b * S_ + (size_t)qi * 64) * HD_;
#pragma unroll
    for (int j = 0; j < 4; ++j) {
        float4 r;
        r.x = o[4 * j + 0] * inv; r.y = o[4 * j + 1] * inv;
        r.z = o[4 * j + 2] * inv; r.w = o[4 * j + 3] * inv;
        *(float4*)&out[qbase + 16 * t + 4 * j] = r;
    }
}

// ------------------------------------------------------------------
extern "C" void kernel_launch(void* const* d_in, const int* in_sizes, int n_in,
                              void* d_out, int out_size, void* d_ws, size_t ws_size,
                              hipStream_t stream)
{
    const float* x  = (const float*)d_in[0];
    const float* wq = (const float*)d_in[1];
    const float* bq = (const float*)d_in[2];
    const float* wk = (const float*)d_in[3];
    const float* bk = (const float*)d_in[4];
    const float* wv = (const float*)d_in[5];
    const float* bv = (const float*)d_in[6];
    float* outp = (float*)d_out;

    // ws layout: qbf | kbf | vt (bf16, n each) | wbf (bf16) | part (fp32)
    const size_t n = (size_t)B_ * S_ * HD_;        // 1048576
    unsigned short* qbf = (unsigned short*)d_ws;
    unsigned short* kbf = qbf + n;
    unsigned short* vtb = kbf + n;
    unsigned short* wbf = vtb + n;                 // 192*1024 bf16
    float* part = (float*)(wbf + (size_t)192 * D_);

    convert_w<<<dim3(192), 256, 0, stream>>>(wq, wk, wv, wbf);
    proj_mfma<<<dim3(B_ * S_ / 32, 2), 256, 0, stream>>>(
        x, wbf, bq, bk, bv, qbf, kbf, vtb);
    flash_splitk<<<dim3(CHUNKS_PER_B, B_), 256, 0, stream>>>(qbf, kbf, vtb, outp, part);
    combine<<<dim3(S_ / 64 - CK, B_), 256, 0, stream>>>(part, outp);
}

// Round 7
// 156.016 us; speedup vs baseline: 1.4184x; 1.4184x over previous
//
#include <hip/hip_runtime.h>
#include <math.h>

#define B_   4
#define S_   4096
#define D_   1024
#define HD_  64

// ---------------- split-K flash constants ----------------
#define CK            8          // k-tiles (of 64 keys) per chunk
#define CHUNKS_PER_B  288        // sum_{qi=0}^{63} (qi/8 + 1)
#define PSTRIDE       68         // floats per row in a partial slot (o[64], m, l, pad)
#define SLOT_F        (64 * PSTRIDE)

typedef float  f32x4  __attribute__((ext_vector_type(4)));
typedef __bf16 bf16x8 __attribute__((ext_vector_type(8)));

static __device__ __forceinline__ unsigned short f2bf(float f) {
    unsigned int u = __float_as_uint(f);
    u += 0x7FFFu + ((u >> 16) & 1u);          // round-to-nearest-even
    return (unsigned short)(u >> 16);
}

// ------------------------------------------------------------------
// Kernel 0: convert wq/wk/wv (fp32 [64][1024]) into wbf (bf16 [192][1024]).
// ------------------------------------------------------------------
__global__ __launch_bounds__(256) void convert_w(
    const float* __restrict__ wq, const float* __restrict__ wk,
    const float* __restrict__ wv, unsigned short* __restrict__ wbf)
{
    const int col = blockIdx.x;            // 0..191
    const int p = col >> 6, h = col & 63;
    const float* src = (p == 0 ? wq : (p == 1 ? wk : wv)) + (size_t)h * D_;
    const int t = threadIdx.x;
    const float4 v = ((const float4*)src)[t];
    ushort4 o;
    o.x = f2bf(v.x); o.y = f2bf(v.y); o.z = f2bf(v.z); o.w = f2bf(v.w);
    *(ushort4*)&wbf[(size_t)col * D_ + 4 * t] = o;
}

// ------------------------------------------------------------------
// Kernel 1: QKV projection via bf16 MFMA (16x16x32), BK=128.
// grid = (512, 2): 32 rows x 96 cols per block. 8 K-iterations
// (vs 16 at BK=64): half the barrier drains, double the loads in
// flight per drain. LDS 34.8 KB -> 4 blocks/CU.
// NO register prefetch (R6 spilled: VGPR 24->56, 36 MB scratch RT).
// Outputs bf16: qbf (pre-scaled 0.125), kbf row-major; vt[b][h][s].
// Fragment layouts (validated R3-R6):
//   A: lane elem j = A[m = lane&15][k = (lane>>4)*8 + j]
//   B: lane elem j = B[k = (lane>>4)*8 + j][n = lane&15]
//   C/D: reg r -> row = (lane>>4)*4 + r, col = lane&15
// ------------------------------------------------------------------
__global__ __launch_bounds__(256) void proj_mfma(
    const float* __restrict__ x, const unsigned short* __restrict__ wbf,
    const float* __restrict__ bq, const float* __restrict__ bk,
    const float* __restrict__ bv,
    unsigned short* __restrict__ qbf, unsigned short* __restrict__ kbf,
    unsigned short* __restrict__ vtb)
{
    __shared__ unsigned short xs[32][136];    // 8704 B  (272B row stride: bank-rotating)
    __shared__ unsigned short wsh[96][136];   // 26112 B

    const int t = threadIdx.x;
    const int w = t >> 6, lane = t & 63;
    const int n = lane & 15, g = lane >> 4;
    const int koff = 8 * g;
    const int rt = w & 1, cg = w >> 1;
    const size_t row0 = (size_t)blockIdx.x * 32;
    const int colbase = 96 * blockIdx.y;

    f32x4 acc[3];
#pragma unroll
    for (int i = 0; i < 3; ++i) acc[i] = (f32x4)0.f;

    for (int chunk = 0; chunk < 8; ++chunk) {
        const int d0 = chunk * 128;
        __syncthreads();
        // stage x: 32 rows x 128 d, fp32 -> bf16 (4 float4/thread)
#pragma unroll
        for (int i = 0; i < 4; ++i) {
            int e = t + i * 256;              // 0..1023 float4
            int r = e >> 5, c4 = (e & 31) * 4;
            float4 v = *(const float4*)&x[(row0 + r) * D_ + d0 + c4];
            ushort4 o;
            o.x = f2bf(v.x); o.y = f2bf(v.y); o.z = f2bf(v.z); o.w = f2bf(v.w);
            *(ushort4*)&xs[r][c4] = o;
        }
        // stage w: 96 cols x 128 d bf16 (6 uint4/thread)
#pragma unroll
        for (int i = 0; i < 6; ++i) {
            int e = t + i * 256;              // 0..1535
            int col = e >> 4, g8 = (e & 15) * 8;
            uint4 v = *(const uint4*)&wbf[(size_t)(colbase + col) * D_ + d0 + g8];
            *(uint4*)&wsh[col][g8] = v;
        }
        __syncthreads();

#pragma unroll
        for (int ks = 0; ks < 4; ++ks) {
            const int k0 = 32 * ks;
            const bf16x8 a = *(const bf16x8*)&xs[16 * rt + n][k0 + koff];
#pragma unroll
            for (int ci = 0; ci < 3; ++ci) {
                const bf16x8 b = *(const bf16x8*)&wsh[48 * cg + 16 * ci + n][k0 + koff];
                acc[ci] = __builtin_amdgcn_mfma_f32_16x16x32_bf16(a, b, acc[ci], 0, 0, 0);
            }
        }
    }

    // epilogue
#pragma unroll
    for (int ci = 0; ci < 3; ++ci) {
        const int gct = 6 * blockIdx.y + 3 * cg + ci;
        const int p = gct >> 2, h0 = (gct & 3) * 16;
        const int h = h0 + n;
        const float bb = (p == 0 ? bq : (p == 1 ? bk : bv))[h];
        if (p == 2) {
            // v transposed: vt[b][h][s], 4 consecutive s packed
            const size_t grow0 = row0 + 16 * rt + 4 * g;
            const int bidx = (int)(grow0 >> 12);
            const int s0 = (int)(grow0 & 4095);
            ushort4 u;
            u.x = f2bf(acc[ci][0] + bb); u.y = f2bf(acc[ci][1] + bb);
            u.z = f2bf(acc[ci][2] + bb); u.w = f2bf(acc[ci][3] + bb);
            *(ushort4*)&vtb[((size_t)bidx * HD_ + h) * S_ + s0] = u;
        } else {
            unsigned short* outp = (p == 0 ? qbf : kbf);
            const float scale = (p == 0) ? 0.125f : 1.0f;
#pragma unroll
            for (int r = 0; r < 4; ++r) {
                const size_t grow = row0 + 16 * rt + 4 * g + r;
                outp[grow * HD_ + h] = f2bf((acc[ci][r] + bb) * scale);
            }
        }
    }
}

// ------------------------------------------------------------------
// Kernel 2: split-K causal flash attention, bf16 MFMA, bf16 inputs.
// Exact R5 structure (best measured). Wave w owns q-rows 16w..16w+15.
// ------------------------------------------------------------------
__global__ __launch_bounds__(256) void flash_splitk(
    const unsigned short* __restrict__ qg, const unsigned short* __restrict__ kg,
    const unsigned short* __restrict__ vt, float* __restrict__ out,
    float* __restrict__ part)
{
    __shared__ unsigned short qsh[64][72];      // 9216 B  Q rows (pre-scaled)
    __shared__ unsigned short ksh[64][72];      // 9216 B  K rows
    __shared__ unsigned short vsh[64][72];      // 9216 B  vT[h][key]
    __shared__ unsigned short psh[4][16][72];   // 9216 B  per-wave P[q][key]

    const int t    = threadIdx.x;
    const int w    = t >> 6;
    const int lane = t & 63;
    const int n    = lane & 15;      // MFMA col index
    const int g    = lane >> 4;      // MFMA row group
    const int koff = 8 * g;
    const int b    = blockIdx.y;

    // decode blockIdx.x -> (qi, c)
    int qi = 0, rem = blockIdx.x;
    while (rem >= ((qi >> 3) + 1)) { rem -= (qi >> 3) + 1; ++qi; }
    const int c   = rem;
    const int kt0 = c * CK;
    const int kt1 = min(qi, kt0 + CK - 1);
    const int nc  = (qi >> 3) + 1;

    const size_t qtile = ((size_t)b * S_ + (size_t)qi * 64) * HD_;

    // stage Q (once): 2 uint4/thread
    {
        const uint4* src = (const uint4*)(qg + qtile);
#pragma unroll
        for (int i = 0; i < 2; ++i) {
            int e = t + i * 256;                // 0..511
            int r = e >> 3, gg = e & 7;
            *(uint4*)&qsh[r][8 * gg] = src[e];
        }
    }

    f32x4 o4[4];
#pragma unroll
    for (int i = 0; i < 4; ++i) o4[i] = (f32x4)0.f;
    float m_r = -INFINITY, l_r = 0.f;

    for (int kt = kt0; kt <= kt1; ++kt) {
        const size_t kvbase = ((size_t)b * S_ + (size_t)kt * 64) * HD_;
        __syncthreads();                        // prev reads done (covers qsh on iter 0)
        {
            const uint4* ksrc = (const uint4*)(kg + kvbase);
#pragma unroll
            for (int i = 0; i < 2; ++i) {
                int e = t + i * 256;
                int r = e >> 3, gg = e & 7;
                *(uint4*)&ksh[r][8 * gg] = ksrc[e];
            }
#pragma unroll
            for (int i = 0; i < 2; ++i) {
                int e = t + i * 256;
                int h = e >> 3, gg = e & 7;     // vt[b][h][kt*64 + 8gg..]
                *(uint4*)&vsh[h][8 * gg] =
                    *(const uint4*)&vt[((size_t)b * HD_ + h) * S_ + kt * 64 + 8 * gg];
            }
        }
        __syncthreads();

        // ---- S^T = K . Q^T : 4 m-tiles (keys) x 16 q ----
        f32x4 sc[4];
#pragma unroll
        for (int mt = 0; mt < 4; ++mt) sc[mt] = (f32x4)0.f;
#pragma unroll
        for (int ks = 0; ks < 2; ++ks) {
            const bf16x8 bq8 = *(const bf16x8*)&qsh[16 * w + n][32 * ks + koff];
#pragma unroll
            for (int mt = 0; mt < 4; ++mt) {
                const bf16x8 ak = *(const bf16x8*)&ksh[16 * mt + n][32 * ks + koff];
                sc[mt] = __builtin_amdgcn_mfma_f32_16x16x32_bf16(ak, bq8, sc[mt], 0, 0, 0);
            }
        }

        // ---- causal mask (diagonal k-tile only) ----
        if (kt == qi) {
            const int qloc = 16 * w + n;
#pragma unroll
            for (int mt = 0; mt < 4; ++mt)
#pragma unroll
                for (int r = 0; r < 4; ++r) {
                    const int kloc = 16 * mt + 4 * g + r;
                    if (kloc > qloc) sc[mt][r] = -INFINITY;
                }
        }

        // ---- online softmax per column q ----
        float mx = -INFINITY;
#pragma unroll
        for (int mt = 0; mt < 4; ++mt)
#pragma unroll
            for (int r = 0; r < 4; ++r) mx = fmaxf(mx, sc[mt][r]);
        mx = fmaxf(mx, __shfl_xor(mx, 16));
        mx = fmaxf(mx, __shfl_xor(mx, 32));

        const float m_new = fmaxf(m_r, mx);
        const float alpha = __expf(m_r - m_new);
        float psum = 0.f;
#pragma unroll
        for (int mt = 0; mt < 4; ++mt)
#pragma unroll
            for (int r = 0; r < 4; ++r) {
                const float p = __expf(sc[mt][r] - m_new);
                sc[mt][r] = p;
                psum += p;
            }
        psum += __shfl_xor(psum, 16);
        psum += __shfl_xor(psum, 32);
        l_r = l_r * alpha + psum;
        m_r = m_new;

        // rescale O rows (row q = 4g+r needs alpha of column 4g+r)
#pragma unroll
        for (int r = 0; r < 4; ++r) {
            const float ar = __shfl(alpha, 4 * g + r);
#pragma unroll
            for (int ht = 0; ht < 4; ++ht) o4[ht][r] *= ar;
        }

        // ---- pack P^T -> per-wave LDS p[q][key] ----
#pragma unroll
        for (int mt = 0; mt < 4; ++mt) {
            ushort4 u;
            u.x = f2bf(sc[mt][0]); u.y = f2bf(sc[mt][1]);
            u.z = f2bf(sc[mt][2]); u.w = f2bf(sc[mt][3]);
            *(ushort4*)&psh[w][n][16 * mt + 4 * g] = u;
        }
        // same-wave RAW on LDS: compiler inserts lgkmcnt wait; no barrier needed

        // ---- O += P . V ----
#pragma unroll
        for (int ks = 0; ks < 2; ++ks) {
            const bf16x8 ap = *(const bf16x8*)&psh[w][n][32 * ks + koff];
#pragma unroll
            for (int ht = 0; ht < 4; ++ht) {
                const bf16x8 bv8 = *(const bf16x8*)&vsh[16 * ht + n][32 * ks + koff];
                o4[ht] = __builtin_amdgcn_mfma_f32_16x16x32_bf16(ap, bv8, o4[ht], 0, 0, 0);
            }
        }
    }

    const size_t qbase = ((size_t)b * S_ + (size_t)qi * 64) * HD_;
    if (nc == 1) {
#pragma unroll
        for (int r = 0; r < 4; ++r) {
            const float lr = __shfl(l_r, 4 * g + r);
            const float inv = 1.f / lr;
            const size_t ob = qbase + (size_t)(16 * w + 4 * g + r) * HD_;
#pragma unroll
            for (int ht = 0; ht < 4; ++ht)
                out[ob + 16 * ht + n] = o4[ht][r] * inv;
        }
    } else {
        const size_t sb = ((size_t)b * CHUNKS_PER_B + blockIdx.x) * SLOT_F;
#pragma unroll
        for (int r = 0; r < 4; ++r) {
            const size_t pb = sb + (size_t)(16 * w + 4 * g + r) * PSTRIDE;
#pragma unroll
            for (int ht = 0; ht < 4; ++ht)
                part[pb + 16 * ht + n] = o4[ht][r];
        }
        if (g == 0) {
            part[sb + (size_t)(16 * w + n) * PSTRIDE + 64] = m_r;
            part[sb + (size_t)(16 * w + n) * PSTRIDE + 65] = l_r;
        }
    }
}

// ------------------------------------------------------------------
// Kernel 3: merge partials for qi >= CK.  grid = (56, B).
// ------------------------------------------------------------------
__global__ __launch_bounds__(256) void combine(
    const float* __restrict__ part, float* __restrict__ out)
{
    const int t  = threadIdx.x;
    const int qr = t >> 2, tc = t & 3;
    const int qi = blockIdx.x + CK;          // 8..63
    const int b  = blockIdx.y;
    const int nc = (qi >> 3) + 1;

    int cum = 0;
    for (int j = 0; j < qi; ++j) cum += (j >> 3) + 1;
    const size_t base0 = ((size_t)b * CHUNKS_PER_B + cum) * SLOT_F;

    float M = -INFINITY;
    for (int c0 = 0; c0 < nc; ++c0)
        M = fmaxf(M, part[base0 + (size_t)c0 * SLOT_F + qr * PSTRIDE + 64]);

    float L = 0.f;
    float o[16];
#pragma unroll
    for (int j = 0; j < 16; ++j) o[j] = 0.f;

    for (int c0 = 0; c0 < nc; ++c0) {
        const size_t sb = base0 + (size_t)c0 * SLOT_F + qr * PSTRIDE;
        const float m_c = part[sb + 64];
        const float l_c = part[sb + 65];
        const float w = __expf(m_c - M);
        L += w * l_c;
#pragma unroll
        for (int j = 0; j < 4; ++j) {
            const float4 ov = *(const float4*)&part[sb + tc * 16 + 4 * j];
            o[4 * j + 0] += w * ov.x; o[4 * j + 1] += w * ov.y;
            o[4 * j + 2] += w * ov.z; o[4 * j + 3] += w * ov.w;
        }
    }

    const float inv = 1.f / L;
    const size_t qbase = ((size_t)b * S_ + (size_t)qi * 64) * HD_;
#pragma unroll
    for (int j = 0; j < 4; ++j) {
        float4 r;
        r.x = o[4 * j + 0] * inv; r.y = o[4 * j + 1] * inv;
        r.z = o[4 * j + 2] * inv; r.w = o[4 * j + 3] * inv;
        *(float4*)&out[qbase + 16 * t + 4 * j] = r;
    }
}

// ------------------------------------------------------------------
extern "C" void kernel_launch(void* const* d_in, const int* in_sizes, int n_in,
                              void* d_out, int out_size, void* d_ws, size_t ws_size,
                              hipStream_t stream)
{
    const float* x  = (const float*)d_in[0];
    const float* wq = (const float*)d_in[1];
    const float* bq = (const float*)d_in[2];
    const float* wk = (const float*)d_in[3];
    const float* bk = (const float*)d_in[4];
    const float* wv = (const float*)d_in[5];
    const float* bv = (const float*)d_in[6];
    float* outp = (float*)d_out;

    // ws layout: qbf | kbf | vt (bf16, n each) | wbf (bf16) | part (fp32)
    const size_t n = (size_t)B_ * S_ * HD_;        // 1048576
    unsigned short* qbf = (unsigned short*)d_ws;
    unsigned short* kbf = qbf + n;
    unsigned short* vtb = kbf + n;
    unsigned short* wbf = vtb + n;                 // 192*1024 bf16
    float* part = (float*)(wbf + (size_t)192 * D_);

    convert_w<<<dim3(192), 256, 0, stream>>>(wq, wk, wv, wbf);
    proj_mfma<<<dim3(B_ * S_ / 32, 2), 256, 0, stream>>>(
        x, wbf, bq, bk, bv, qbf, kbf, vtb);
    flash_splitk<<<dim3(CHUNKS_PER_B, B_), 256, 0, stream>>>(qbf, kbf, vtb, outp, part);
    combine<<<dim3(S_ / 64 - CK, B_), 256, 0, stream>>>(part, outp);
}